// Round 9
// baseline (484.833 us; speedup 1.0000x reference)
//
#include <hip/hip_runtime.h>
#include <hip/hip_bf16.h>

#define D128 128
#define NEG_SLOPE 0.2f

typedef __attribute__((ext_vector_type(8))) short bf16x8;
typedef __attribute__((ext_vector_type(4))) float f32x4;

__device__ inline float bf2f(unsigned short u) {
    return __uint_as_float(((unsigned)u) << 16);
}
__device__ inline unsigned short f2bf(float f) {  // RTNE
    unsigned u = __float_as_uint(f);
    unsigned r = (u + 0x7fffu + ((u >> 16) & 1u)) >> 16;
    return (unsigned short)r;
}

// ---------------------------------------------------------------------------
// CSR build
// ---------------------------------------------------------------------------
__global__ void zero_int_kernel(int* __restrict__ p, int n) {
    int i = blockIdx.x * blockDim.x + threadIdx.x;
    if (i < n) p[i] = 0;
}

__global__ void count_kernel(const int* __restrict__ dst, int E, int* __restrict__ cnt) {
    int e = blockIdx.x * blockDim.x + threadIdx.x;
    if (e < E) atomicAdd(&cnt[dst[e]], 1);
}

#define SB 256
#define SCAN_CHUNK 2048  // SB * 8

__global__ __launch_bounds__(SB) void scan_local_kernel(const int* __restrict__ cnt,
                                                        int* __restrict__ off,
                                                        int* __restrict__ partials, int N) {
    __shared__ int lds[SB];
    const int b = blockIdx.x;
    const int t = threadIdx.x;
    const int base = b * SCAN_CHUNK + t * 8;
    int v[8];
    int s = 0;
#pragma unroll
    for (int j = 0; j < 8; ++j) {
        int i = base + j;
        v[j] = (i < N) ? cnt[i] : 0;
        s += v[j];
    }
    lds[t] = s;
    __syncthreads();
    for (int d = 1; d < SB; d <<= 1) {
        int y = (t >= d) ? lds[t - d] : 0;
        __syncthreads();
        lds[t] += y;
        __syncthreads();
    }
    int pref = lds[t] - s;
#pragma unroll
    for (int j = 0; j < 8; ++j) {
        int i = base + j;
        if (i < N) off[i] = pref;
        pref += v[j];
    }
    if (t == SB - 1) partials[b] = lds[t];
}

__global__ __launch_bounds__(64) void scan_partials_kernel(int* __restrict__ partials,
                                                           int* __restrict__ pp, int NB,
                                                           int* __restrict__ off, int N) {
    __shared__ int lds[64];
    int t = threadIdx.x;
    int v = (t < NB) ? partials[t] : 0;
    lds[t] = v;
    __syncthreads();
    for (int d = 1; d < 64; d <<= 1) {
        int y = (t >= d) ? lds[t - d] : 0;
        __syncthreads();
        lds[t] += y;
        __syncthreads();
    }
    pp[t] = lds[t] - v;
    if (t == 63) off[N] = lds[63];
}

__global__ void scan_add_kernel(int* __restrict__ off, int* __restrict__ cur,
                                const int* __restrict__ pp, int N) {
    int i = blockIdx.x * blockDim.x + threadIdx.x;
    if (i < N) {
        int o = off[i] + pp[i / SCAN_CHUNK];
        off[i] = o;
        cur[i] = o;
    }
}

__global__ void fill_kernel(const int* __restrict__ src, const int* __restrict__ dst, int E,
                            int* __restrict__ cur, int* __restrict__ csr_src,
                            int* __restrict__ csr_dst) {
    int e = blockIdx.x * blockDim.x + threadIdx.x;
    if (e < E) {
        int d = dst[e];
        int p = atomicAdd(&cur[d], 1);
        csr_src[p] = src[e];
        csr_dst[p] = d;
    }
}

// ---------------------------------------------------------------------------
// W repack into MFMA B-fragment order, split hi/lo bf16.
// ---------------------------------------------------------------------------
__global__ __launch_bounds__(256) void wrepack_kernel(const float* __restrict__ W,
                                                      unsigned short* __restrict__ Wb) {
    int i = blockIdx.x * 256 + threadIdx.x;  // 0..16383
    if (i >= 16384) return;
    int j = i & 7;
    int l = (i >> 3) & 63;
    int kk = (i >> 9) & 3;
    int ct = i >> 11;
    int k = kk * 32 + ((l >> 4) & 3) * 8 + j;
    int c = ct * 16 + (l & 15);
    float w = W[k * 128 + c];
    unsigned short hi = f2bf(w);
    unsigned short lo = f2bf(w - bf2f(hi));
    Wb[i] = hi;
    Wb[16384 + i] = lo;
}

// ---------------------------------------------------------------------------
// MFMA GEMM (split-bf16 ~ fp32 accuracy) fused with attention scalars.
// 8 waves/block, 128 rows/block.  W fragments staged once into LDS (64 KB);
// per-wave B reads are ds_read_b128 (pipelined), not serialized L2 loads.
// ---------------------------------------------------------------------------
template <int H, bool SPLIT>
__global__ __launch_bounds__(512) void gemm_mfma_kernel(const float* __restrict__ X0,
                                                        const float* __restrict__ X1, int split,
                                                        const unsigned short* __restrict__ Wb,
                                                        const float* __restrict__ att_s,
                                                        const float* __restrict__ att_d,
                                                        unsigned short* __restrict__ hb,
                                                        float* __restrict__ a_s,
                                                        float* __restrict__ a_d, int N) {
    __shared__ unsigned short wlds[32768];  // 64 KB: hi [0,16384), lo [16384,32768)
    const int t = threadIdx.x;
    const int lane = t & 63;
    const int wave = t >> 6;
    const int row0 = blockIdx.x * 128 + wave * 16;

    // stage W fragments (coalesced int4 copy)
    for (int i = t; i < 4096; i += 512)
        ((int4*)wlds)[i] = ((const int4*)Wb)[i];

    const int lr = lane & 15;
    const int lk = lane >> 4;

    int arow = row0 + lr;
    if (arow >= N) arow = N - 1;  // clamp; padded rows never stored
    const float* xrow;
    if (SPLIT)
        xrow = (arow < split) ? &X0[(size_t)arow * 128] : &X1[(size_t)(arow - split) * 128];
    else
        xrow = &X0[(size_t)arow * 128];

    bf16x8 ahi[4], alo[4];
#pragma unroll
    for (int kk = 0; kk < 4; ++kk) {
        const float* ap = &xrow[kk * 32 + lk * 8];
        float4 v0 = *(const float4*)ap;
        float4 v1 = *(const float4*)(ap + 4);
        float f[8] = {v0.x, v0.y, v0.z, v0.w, v1.x, v1.y, v1.z, v1.w};
#pragma unroll
        for (int j = 0; j < 8; ++j) {
            unsigned short hi = f2bf(f[j]);
            unsigned short lo = f2bf(f[j] - bf2f(hi));
            ((short*)&ahi[kk])[j] = (short)hi;
            ((short*)&alo[kk])[j] = (short)lo;
        }
    }

    f32x4 acc[8];
#pragma unroll
    for (int ct = 0; ct < 8; ++ct) acc[ct] = (f32x4){0.f, 0.f, 0.f, 0.f};

    __syncthreads();

#pragma unroll
    for (int kk = 0; kk < 4; ++kk) {
#pragma unroll
        for (int ct = 0; ct < 8; ++ct) {
            const int fo = ((ct * 4 + kk) * 64 + lane) * 8;
            bf16x8 bhi = *(const bf16x8*)&wlds[fo];
            bf16x8 blo = *(const bf16x8*)&wlds[16384 + fo];
            acc[ct] = __builtin_amdgcn_mfma_f32_16x16x32_bf16(ahi[kk], bhi, acc[ct], 0, 0, 0);
            acc[ct] = __builtin_amdgcn_mfma_f32_16x16x32_bf16(ahi[kk], blo, acc[ct], 0, 0, 0);
            acc[ct] = __builtin_amdgcn_mfma_f32_16x16x32_bf16(alo[kk], bhi, acc[ct], 0, 0, 0);
        }
    }

    float ps[4][H], pd[4][H];
#pragma unroll
    for (int r = 0; r < 4; ++r)
#pragma unroll
        for (int h = 0; h < H; ++h) { ps[r][h] = 0.f; pd[r][h] = 0.f; }

#pragma unroll
    for (int ct = 0; ct < 8; ++ct) {
        float as_c = att_s[ct * 16 + lr];
        float ad_c = att_d[ct * 16 + lr];
        const int h = (ct * H) >> 3;
#pragma unroll
        for (int r = 0; r < 4; ++r) {
            float v = acc[ct][r];
            int row = row0 + lk * 4 + r;
            if (row < N) hb[(size_t)row * 128 + ct * 16 + lr] = f2bf(v);
            ps[r][h] += v * as_c;
            pd[r][h] += v * ad_c;
        }
    }

#pragma unroll
    for (int m = 1; m < 16; m <<= 1) {
#pragma unroll
        for (int r = 0; r < 4; ++r)
#pragma unroll
            for (int h = 0; h < H; ++h) {
                ps[r][h] += __shfl_xor(ps[r][h], m);
                pd[r][h] += __shfl_xor(pd[r][h], m);
            }
    }
    if (lr == 0) {
#pragma unroll
        for (int r = 0; r < 4; ++r) {
            int row = row0 + lk * 4 + r;
            if (row < N) {
                if (H == 4) {
                    *(float4*)&a_s[(size_t)row * 4] =
                        make_float4(ps[r][0], ps[r][1], ps[r][2], ps[r][3]);
                    *(float4*)&a_d[(size_t)row * 4] =
                        make_float4(pd[r][0], pd[r][1], pd[r][2], pd[r][3]);
                } else {
                    a_s[row] = ps[r][0];
                    a_d[row] = pd[r][0];
                }
            }
        }
    }
}

// ---------------------------------------------------------------------------
// per-edge softmax numerator p = exp(leaky_relu(a_s[src]+a_d[dst]))
// ---------------------------------------------------------------------------
__global__ void pk4_kernel(const int* __restrict__ csr_src, const int* __restrict__ csr_dst,
                           const float* __restrict__ a_s, const float* __restrict__ a_d,
                           float* __restrict__ pbuf, int E) {
    int i = blockIdx.x * blockDim.x + threadIdx.x;
    if (i >= E) return;
    int s = csr_src[i], d = csr_dst[i];
    const float4 as4 = *(const float4*)&a_s[(size_t)s * 4];
    const float4 ad4 = *(const float4*)&a_d[(size_t)d * 4];
    float4 o;
    float lg;
    lg = as4.x + ad4.x; lg = lg >= 0.f ? lg : NEG_SLOPE * lg; o.x = expf(lg);
    lg = as4.y + ad4.y; lg = lg >= 0.f ? lg : NEG_SLOPE * lg; o.y = expf(lg);
    lg = as4.z + ad4.z; lg = lg >= 0.f ? lg : NEG_SLOPE * lg; o.z = expf(lg);
    lg = as4.w + ad4.w; lg = lg >= 0.f ? lg : NEG_SLOPE * lg; o.w = expf(lg);
    *(float4*)&pbuf[(size_t)i * 4] = o;
}

__global__ void pk1_kernel(const int* __restrict__ csr_src, const int* __restrict__ csr_dst,
                           const float* __restrict__ a_s, const float* __restrict__ a_d,
                           float* __restrict__ pbuf, int E) {
    int i = blockIdx.x * blockDim.x + threadIdx.x;
    if (i >= E) return;
    float lg = a_s[csr_src[i]] + a_d[csr_dst[i]];
    lg = lg >= 0.f ? lg : NEG_SLOPE * lg;
    pbuf[i] = expf(lg);
}

// ---------------------------------------------------------------------------
// aggregation + bias + ELU + residual + LayerNorm.  One wave per node.
// ---------------------------------------------------------------------------
template <int H, bool RES>
__global__ __launch_bounds__(256) void agg_kernel(const unsigned short* __restrict__ hb,
                                                  const float* __restrict__ pbuf,
                                                  const int* __restrict__ off,
                                                  const int* __restrict__ csr_src,
                                                  const float* __restrict__ xprev,
                                                  const float* __restrict__ bias,
                                                  const float* __restrict__ ln_g,
                                                  const float* __restrict__ ln_b,
                                                  float* __restrict__ xout, int N) {
    const int lane = threadIdx.x & 63;
    const int n = blockIdx.x * 4 + (threadIdx.x >> 6);
    if (n >= N) return;
    const int c2 = lane * 2;
    const int head = (c2 * H) >> 7;
    const int base = off[n];
    const int deg = off[n + 1] - base;

    float a0 = 0.f, a1 = 0.f;
    float b0 = 0.f, b1 = 0.f;
    float c0 = 0.f, c1 = 0.f;
    float d0 = 0.f, d1 = 0.f;
    float psum = 0.f;

    for (int e0 = 0; e0 < deg; e0 += 64) {
        const int ce = min(64, deg - e0);
        int myidx = 0;
        if (lane < ce) myidx = csr_src[base + e0 + lane];
        const float* pb = &pbuf[(size_t)(base + e0) * H + head];
        int e = 0;
        for (; e + 3 < ce; e += 4) {
            int s0 = __shfl(myidx, e);
            int s1 = __shfl(myidx, e + 1);
            int s2 = __shfl(myidx, e + 2);
            int s3 = __shfl(myidx, e + 3);
            float p0 = pb[(size_t)(e + 0) * H];
            float p1 = pb[(size_t)(e + 1) * H];
            float p2 = pb[(size_t)(e + 2) * H];
            float p3 = pb[(size_t)(e + 3) * H];
            unsigned hv0 = *(const unsigned*)&hb[((size_t)s0 << 7) + c2];
            unsigned hv1 = *(const unsigned*)&hb[((size_t)s1 << 7) + c2];
            unsigned hv2 = *(const unsigned*)&hb[((size_t)s2 << 7) + c2];
            unsigned hv3 = *(const unsigned*)&hb[((size_t)s3 << 7) + c2];
            psum += (p0 + p1) + (p2 + p3);
            a0 = fmaf(p0, bf2f((unsigned short)hv0), a0);
            a1 = fmaf(p0, bf2f((unsigned short)(hv0 >> 16)), a1);
            b0 = fmaf(p1, bf2f((unsigned short)hv1), b0);
            b1 = fmaf(p1, bf2f((unsigned short)(hv1 >> 16)), b1);
            c0 = fmaf(p2, bf2f((unsigned short)hv2), c0);
            c1 = fmaf(p2, bf2f((unsigned short)(hv2 >> 16)), c1);
            d0 = fmaf(p3, bf2f((unsigned short)hv3), d0);
            d1 = fmaf(p3, bf2f((unsigned short)(hv3 >> 16)), d1);
        }
        for (; e < ce; ++e) {
            int s0 = __shfl(myidx, e);
            float p0 = pb[(size_t)e * H];
            unsigned hv0 = *(const unsigned*)&hb[((size_t)s0 << 7) + c2];
            psum += p0;
            a0 = fmaf(p0, bf2f((unsigned short)hv0), a0);
            a1 = fmaf(p0, bf2f((unsigned short)(hv0 >> 16)), a1);
        }
    }
    a0 = (a0 + b0) + (c0 + d0);
    a1 = (a1 + b1) + (c1 + d1);

    float inv = 1.0f / (psum + 1e-16f);
    float acc0 = a0 * inv + bias[c2];
    float acc1 = a1 * inv + bias[c2 + 1];
    acc0 = acc0 > 0.f ? acc0 : (expf(acc0) - 1.0f);
    acc1 = acc1 > 0.f ? acc1 : (expf(acc1) - 1.0f);
    if (RES) {
        float2 xp = *(const float2*)&xprev[((size_t)n << 7) + c2];
        acc0 += xp.x;
        acc1 += xp.y;
    }

    float s1v = acc0 + acc1;
    float s2v = acc0 * acc0 + acc1 * acc1;
#pragma unroll
    for (int m = 1; m < 64; m <<= 1) {
        s1v += __shfl_xor(s1v, m);
        s2v += __shfl_xor(s2v, m);
    }
    float mu = s1v * (1.0f / 128.0f);
    float var = s2v * (1.0f / 128.0f) - mu * mu;
    float rstd = rsqrtf(var + 1e-5f);
    float2 o;
    o.x = (acc0 - mu) * rstd * ln_g[c2] + ln_b[c2];
    o.y = (acc1 - mu) * rstd * ln_g[c2 + 1] + ln_b[c2 + 1];
    *(float2*)&xout[((size_t)n << 7) + c2] = o;
}

// ---------------------------------------------------------------------------
// fused prediction MLP: 16 rows per 256-thread block (higher TLP),
// 2x4 micro-tile, 8-deep weight prefetch.
// ---------------------------------------------------------------------------
__global__ __launch_bounds__(256) void mlp_kernel(const float* __restrict__ x,
                                                  const int* __restrict__ uidx,
                                                  const int* __restrict__ vidx, int num_users,
                                                  const float* __restrict__ mw1,
                                                  const float* __restrict__ mb1,
                                                  const float* __restrict__ mw2,
                                                  const float* __restrict__ mb2,
                                                  const float* __restrict__ mw3,
                                                  const float* __restrict__ mb3,
                                                  float* __restrict__ out, int B) {
    __shared__ float xs[16][128];
    __shared__ float h1s[16][128];
    __shared__ float h2s[16][66];
    const int t = threadIdx.x;
    const int b0 = blockIdx.x * 16;
    const int c0 = (t & 31) * 4;
    const int r0 = (t >> 5) * 2;

    float acc[2][4];
    const float4 bias1 = *(const float4*)&mb1[c0];
#pragma unroll
    for (int r = 0; r < 2; ++r) {
        acc[r][0] = bias1.x; acc[r][1] = bias1.y;
        acc[r][2] = bias1.z; acc[r][3] = bias1.w;
    }

    for (int i = t; i < 16 * 32; i += 256) {
        int r = i >> 5, c = (i & 31) * 4;
        int b = b0 + r;
        float4 v = make_float4(0.f, 0.f, 0.f, 0.f);
        if (b < B) v = *(const float4*)&x[(size_t)uidx[b] * 128 + c];
        *(float4*)&xs[r][c] = v;
    }
    __syncthreads();
    for (int k = 0; k < 128; k += 8) {
        float4 w[8];
#pragma unroll
        for (int j = 0; j < 8; ++j) w[j] = *(const float4*)&mw1[(k + j) * 128 + c0];
#pragma unroll
        for (int j = 0; j < 8; ++j)
#pragma unroll
            for (int r = 0; r < 2; ++r) {
                float xv = xs[r0 + r][k + j];
                acc[r][0] += xv * w[j].x; acc[r][1] += xv * w[j].y;
                acc[r][2] += xv * w[j].z; acc[r][3] += xv * w[j].w;
            }
    }
    __syncthreads();

    for (int i = t; i < 16 * 32; i += 256) {
        int r = i >> 5, c = (i & 31) * 4;
        int b = b0 + r;
        float4 v = make_float4(0.f, 0.f, 0.f, 0.f);
        if (b < B) v = *(const float4*)&x[(size_t)(vidx[b] + num_users) * 128 + c];
        *(float4*)&xs[r][c] = v;
    }
    __syncthreads();
    for (int k = 0; k < 128; k += 8) {
        float4 w[8];
#pragma unroll
        for (int j = 0; j < 8; ++j) w[j] = *(const float4*)&mw1[(128 + k + j) * 128 + c0];
#pragma unroll
        for (int j = 0; j < 8; ++j)
#pragma unroll
            for (int r = 0; r < 2; ++r) {
                float xv = xs[r0 + r][k + j];
                acc[r][0] += xv * w[j].x; acc[r][1] += xv * w[j].y;
                acc[r][2] += xv * w[j].z; acc[r][3] += xv * w[j].w;
            }
    }

#pragma unroll
    for (int r = 0; r < 2; ++r) {
        float4 h;
        h.x = fmaxf(acc[r][0], 0.f); h.y = fmaxf(acc[r][1], 0.f);
        h.z = fmaxf(acc[r][2], 0.f); h.w = fmaxf(acc[r][3], 0.f);
        *(float4*)&h1s[r0 + r][c0] = h;
    }
    __syncthreads();

    const int c2 = (t & 31) * 2;
    float acc2[2][2];
    const float b2x = mb2[c2], b2y = mb2[c2 + 1];
#pragma unroll
    for (int r = 0; r < 2; ++r) { acc2[r][0] = b2x; acc2[r][1] = b2y; }

    for (int k = 0; k < 128; k += 8) {
        float2 w[8];
#pragma unroll
        for (int j = 0; j < 8; ++j) w[j] = *(const float2*)&mw2[(k + j) * 64 + c2];
#pragma unroll
        for (int r = 0; r < 2; ++r) {
            float4 h0 = *(const float4*)&h1s[r0 + r][k];
            float4 h1 = *(const float4*)&h1s[r0 + r][k + 4];
            acc2[r][0] += h0.x * w[0].x + h0.y * w[1].x + h0.z * w[2].x + h0.w * w[3].x +
                          h1.x * w[4].x + h1.y * w[5].x + h1.z * w[6].x + h1.w * w[7].x;
            acc2[r][1] += h0.x * w[0].y + h0.y * w[1].y + h0.z * w[2].y + h0.w * w[3].y +
                          h1.x * w[4].y + h1.y * w[5].y + h1.z * w[6].y + h1.w * w[7].y;
        }
    }

#pragma unroll
    for (int r = 0; r < 2; ++r) {
        float2 h;
        h.x = fmaxf(acc2[r][0], 0.f);
        h.y = fmaxf(acc2[r][1], 0.f);
        *(float2*)&h2s[r0 + r][c2] = h;
    }
    __syncthreads();

    // ---- layer 3: 64 -> 1; 16 threads per row ----
    {
        const int row = t >> 4, q = t & 15;
        float s = 0.f;
        const float* hrow = &h2s[row][q * 4];
        const float* wrow = &mw3[q * 4];
#pragma unroll
        for (int kk = 0; kk < 4; ++kk) s += hrow[kk] * wrow[kk];
        s += __shfl_xor(s, 1);
        s += __shfl_xor(s, 2);
        s += __shfl_xor(s, 4);
        s += __shfl_xor(s, 8);
        int b = b0 + row;
        if (q == 0 && b < B) out[b] = 1.0f / (1.0f + expf(-(s + mb3[0])));
    }
}

// ---------------------------------------------------------------------------
// launcher
// ---------------------------------------------------------------------------
extern "C" void kernel_launch(void* const* d_in, const int* in_sizes, int n_in,
                              void* d_out, int out_size, void* d_ws, size_t ws_size,
                              hipStream_t stream) {
    const int* uidx = (const int*)d_in[0];
    const int* vidx = (const int*)d_in[1];
    const int* eidx = (const int*)d_in[2];
    const float* utab = (const float*)d_in[3];
    const float* itab = (const float*)d_in[4];
    const float* W0 = (const float*)d_in[5];
    const float* as0 = (const float*)d_in[6];
    const float* ad0 = (const float*)d_in[7];
    const float* bb0 = (const float*)d_in[8];
    const float* W1 = (const float*)d_in[9];
    const float* as1 = (const float*)d_in[10];
    const float* ad1 = (const float*)d_in[11];
    const float* bb1 = (const float*)d_in[12];
    const float* W2 = (const float*)d_in[13];
    const float* as2 = (const float*)d_in[14];
    const float* ad2 = (const float*)d_in[15];
    const float* bb2 = (const float*)d_in[16];
    const float* ln_g = (const float*)d_in[17];
    const float* ln_b = (const float*)d_in[18];
    const float* mw1 = (const float*)d_in[19];
    const float* mb1 = (const float*)d_in[20];
    const float* mw2 = (const float*)d_in[21];
    const float* mb2 = (const float*)d_in[22];
    const float* mw3 = (const float*)d_in[23];
    const float* mb3 = (const float*)d_in[24];

    const int B = in_sizes[0];
    const int E = in_sizes[2] / 2;
    const int num_users = in_sizes[3] / D128;
    const int num_items = in_sizes[4] / D128;
    const int N = num_users + num_items;
    const int* esrc = eidx;
    const int* edst = eidx + E;

    size_t wsoff = 0;
    auto alloc = [&](size_t bytes) {
        void* p = (char*)d_ws + wsoff;
        wsoff += (bytes + 255) & ~(size_t)255;
        return p;
    };
    float* bufA = (float*)alloc((size_t)N * 128 * 4);
    float* bufB = (float*)alloc((size_t)N * 128 * 4);
    unsigned short* hb = (unsigned short*)alloc((size_t)N * 128 * 2);
    float* aS = (float*)alloc((size_t)N * 4 * 4);
    float* aD = (float*)alloc((size_t)N * 4 * 4);
    float* pbuf = (float*)alloc((size_t)E * 4 * 4);
    int* cnt = (int*)alloc((size_t)(N + 1) * 4);
    int* off = (int*)alloc((size_t)(N + 1) * 4);
    int* cur = (int*)alloc((size_t)(N + 1) * 4);
    int* csr_src = (int*)alloc((size_t)E * 4);
    int* csr_dst = (int*)alloc((size_t)E * 4);
    int* partials = (int*)alloc(64 * 4);
    int* pp = (int*)alloc(64 * 4);
    unsigned short* wb0 = (unsigned short*)alloc(2 * 16384 * 2);
    unsigned short* wb1 = (unsigned short*)alloc(2 * 16384 * 2);
    unsigned short* wb2 = (unsigned short*)alloc(2 * 16384 * 2);
    (void)ws_size;

    wrepack_kernel<<<64, 256, 0, stream>>>(W0, wb0);
    wrepack_kernel<<<64, 256, 0, stream>>>(W1, wb1);
    wrepack_kernel<<<64, 256, 0, stream>>>(W2, wb2);

    const int NB = (N + SCAN_CHUNK - 1) / SCAN_CHUNK;
    zero_int_kernel<<<(N + 255) / 256, 256, 0, stream>>>(cnt, N);
    count_kernel<<<(E + 255) / 256, 256, 0, stream>>>(edst, E, cnt);
    scan_local_kernel<<<NB, SB, 0, stream>>>(cnt, off, partials, N);
    scan_partials_kernel<<<1, 64, 0, stream>>>(partials, pp, NB, off, N);
    scan_add_kernel<<<(N + 255) / 256, 256, 0, stream>>>(off, cur, pp, N);
    fill_kernel<<<(E + 255) / 256, 256, 0, stream>>>(esrc, edst, E, cur, csr_src, csr_dst);

    const int gemm_grid = (N + 127) / 128;
    const int egrid = (E + 255) / 256;
    const int agrid = (N + 3) / 4;

    // ---- layer 0 (H=4, no residual; X = virtual concat of tables) ----
    gemm_mfma_kernel<4, true><<<gemm_grid, 512, 0, stream>>>(utab, itab, num_users, wb0, as0,
                                                             ad0, hb, aS, aD, N);
    pk4_kernel<<<egrid, 256, 0, stream>>>(csr_src, csr_dst, aS, aD, pbuf, E);
    agg_kernel<4, false><<<agrid, 256, 0, stream>>>(hb, pbuf, off, csr_src, nullptr, bb0, ln_g,
                                                    ln_b, bufB, N);
    // ---- layer 1 (H=4, residual) ----
    gemm_mfma_kernel<4, false><<<gemm_grid, 512, 0, stream>>>(bufB, nullptr, 0, wb1, as1, ad1,
                                                              hb, aS, aD, N);
    pk4_kernel<<<egrid, 256, 0, stream>>>(csr_src, csr_dst, aS, aD, pbuf, E);
    agg_kernel<4, true><<<agrid, 256, 0, stream>>>(hb, pbuf, off, csr_src, bufB, bb1, ln_g,
                                                   ln_b, bufA, N);
    // ---- layer 2 (H=1, residual) ----
    gemm_mfma_kernel<1, false><<<gemm_grid, 512, 0, stream>>>(bufA, nullptr, 0, wb2, as2, ad2,
                                                              hb, aS, aD, N);
    pk1_kernel<<<egrid, 256, 0, stream>>>(csr_src, csr_dst, aS, aD, pbuf, E);
    agg_kernel<1, true><<<agrid, 256, 0, stream>>>(hb, pbuf, off, csr_src, bufA, bb2, ln_g,
                                                   ln_b, bufB, N);

    // ---- prediction MLP ----
    mlp_kernel<<<(B + 15) / 16, 256, 0, stream>>>(bufB, uidx, vidx, num_users, mw1, mb1, mw2,
                                                  mb2, mw3, mb3, (float*)d_out, B);
}

// Round 10
// 277.657 us; speedup vs baseline: 1.7462x; 1.7462x over previous
//
#include <hip/hip_runtime.h>
#include <hip/hip_bf16.h>

#define D128 128
#define NEG_SLOPE 0.2f

typedef __attribute__((ext_vector_type(8))) short bf16x8;
typedef __attribute__((ext_vector_type(4))) float f32x4;

__device__ inline float bf2f(unsigned short u) {
    return __uint_as_float(((unsigned)u) << 16);
}
__device__ inline unsigned short f2bf(float f) {  // RTNE
    unsigned u = __float_as_uint(f);
    unsigned r = (u + 0x7fffu + ((u >> 16) & 1u)) >> 16;
    return (unsigned short)r;
}

// ---------------------------------------------------------------------------
// CSR build
// ---------------------------------------------------------------------------
__global__ void zero_int_kernel(int* __restrict__ p, int n) {
    int i = blockIdx.x * blockDim.x + threadIdx.x;
    if (i < n) p[i] = 0;
}

__global__ void count_kernel(const int* __restrict__ dst, int E, int* __restrict__ cnt) {
    int e = blockIdx.x * blockDim.x + threadIdx.x;
    if (e < E) atomicAdd(&cnt[dst[e]], 1);
}

#define SB 256
#define SCAN_CHUNK 2048  // SB * 8

__global__ __launch_bounds__(SB) void scan_local_kernel(const int* __restrict__ cnt,
                                                        int* __restrict__ off,
                                                        int* __restrict__ partials, int N) {
    __shared__ int lds[SB];
    const int b = blockIdx.x;
    const int t = threadIdx.x;
    const int base = b * SCAN_CHUNK + t * 8;
    int v[8];
    int s = 0;
#pragma unroll
    for (int j = 0; j < 8; ++j) {
        int i = base + j;
        v[j] = (i < N) ? cnt[i] : 0;
        s += v[j];
    }
    lds[t] = s;
    __syncthreads();
    for (int d = 1; d < SB; d <<= 1) {
        int y = (t >= d) ? lds[t - d] : 0;
        __syncthreads();
        lds[t] += y;
        __syncthreads();
    }
    int pref = lds[t] - s;
#pragma unroll
    for (int j = 0; j < 8; ++j) {
        int i = base + j;
        if (i < N) off[i] = pref;
        pref += v[j];
    }
    if (t == SB - 1) partials[b] = lds[t];
}

__global__ __launch_bounds__(64) void scan_partials_kernel(int* __restrict__ partials,
                                                           int* __restrict__ pp, int NB,
                                                           int* __restrict__ off, int N) {
    __shared__ int lds[64];
    int t = threadIdx.x;
    int v = (t < NB) ? partials[t] : 0;
    lds[t] = v;
    __syncthreads();
    for (int d = 1; d < 64; d <<= 1) {
        int y = (t >= d) ? lds[t - d] : 0;
        __syncthreads();
        lds[t] += y;
        __syncthreads();
    }
    pp[t] = lds[t] - v;
    if (t == 63) off[N] = lds[63];
}

__global__ void scan_add_kernel(int* __restrict__ off, int* __restrict__ cur,
                                const int* __restrict__ pp, int N) {
    int i = blockIdx.x * blockDim.x + threadIdx.x;
    if (i < N) {
        int o = off[i] + pp[i / SCAN_CHUNK];
        off[i] = o;
        cur[i] = o;
    }
}

__global__ void fill_kernel(const int* __restrict__ src, const int* __restrict__ dst, int E,
                            int* __restrict__ cur, int* __restrict__ csr_src,
                            int* __restrict__ csr_dst) {
    int e = blockIdx.x * blockDim.x + threadIdx.x;
    if (e < E) {
        int d = dst[e];
        int p = atomicAdd(&cur[d], 1);
        csr_src[p] = src[e];
        csr_dst[p] = d;
    }
}

// ---------------------------------------------------------------------------
// W repack into MFMA B-fragment order, split hi/lo bf16 (for GAT layers).
// ---------------------------------------------------------------------------
__global__ __launch_bounds__(256) void wrepack_kernel(const float* __restrict__ W,
                                                      unsigned short* __restrict__ Wb) {
    int i = blockIdx.x * 256 + threadIdx.x;  // 0..16383
    if (i >= 16384) return;
    int j = i & 7;
    int l = (i >> 3) & 63;
    int kk = (i >> 9) & 3;
    int ct = i >> 11;
    int k = kk * 32 + ((l >> 4) & 3) * 8 + j;
    int c = ct * 16 + (l & 15);
    float w = W[k * 128 + c];
    unsigned short hi = f2bf(w);
    unsigned short lo = f2bf(w - bf2f(hi));
    Wb[i] = hi;
    Wb[16384 + i] = lo;
}

// generic bf16-hi-only repack for MLP weights: W[K,C] -> frag order (ct*KK+kk)
__global__ __launch_bounds__(256) void wrepack_bf16_kernel(const float* __restrict__ W,
                                                           unsigned short* __restrict__ Wf,
                                                           int K, int C) {
    int total = K * C;
    int i = blockIdx.x * 256 + threadIdx.x;
    if (i >= total) return;
    int j = i & 7;
    int l = (i >> 3) & 63;
    int kkct = i >> 9;
    int KK = K >> 5;
    int kk = kkct % KK;
    int ct = kkct / KK;
    int k = kk * 32 + (l >> 4) * 8 + j;
    int c = ct * 16 + (l & 15);
    Wf[i] = f2bf(W[k * C + c]);
}

// ---------------------------------------------------------------------------
// MFMA GEMM (split-bf16 ~ fp32 accuracy) fused with attention scalars.
// 8 waves/block, 128 rows/block, W fragments staged in LDS.
// ---------------------------------------------------------------------------
template <int H, bool SPLIT>
__global__ __launch_bounds__(512) void gemm_mfma_kernel(const float* __restrict__ X0,
                                                        const float* __restrict__ X1, int split,
                                                        const unsigned short* __restrict__ Wb,
                                                        const float* __restrict__ att_s,
                                                        const float* __restrict__ att_d,
                                                        unsigned short* __restrict__ hb,
                                                        float* __restrict__ a_s,
                                                        float* __restrict__ a_d, int N) {
    __shared__ unsigned short wlds[32768];  // 64 KB: hi [0,16384), lo [16384,32768)
    const int t = threadIdx.x;
    const int lane = t & 63;
    const int wave = t >> 6;
    const int row0 = blockIdx.x * 128 + wave * 16;

    for (int i = t; i < 4096; i += 512)
        ((int4*)wlds)[i] = ((const int4*)Wb)[i];

    const int lr = lane & 15;
    const int lk = lane >> 4;

    int arow = row0 + lr;
    if (arow >= N) arow = N - 1;  // clamp; padded rows never stored
    const float* xrow;
    if (SPLIT)
        xrow = (arow < split) ? &X0[(size_t)arow * 128] : &X1[(size_t)(arow - split) * 128];
    else
        xrow = &X0[(size_t)arow * 128];

    bf16x8 ahi[4], alo[4];
#pragma unroll
    for (int kk = 0; kk < 4; ++kk) {
        const float* ap = &xrow[kk * 32 + lk * 8];
        float4 v0 = *(const float4*)ap;
        float4 v1 = *(const float4*)(ap + 4);
        float f[8] = {v0.x, v0.y, v0.z, v0.w, v1.x, v1.y, v1.z, v1.w};
#pragma unroll
        for (int j = 0; j < 8; ++j) {
            unsigned short hi = f2bf(f[j]);
            unsigned short lo = f2bf(f[j] - bf2f(hi));
            ((short*)&ahi[kk])[j] = (short)hi;
            ((short*)&alo[kk])[j] = (short)lo;
        }
    }

    f32x4 acc[8];
#pragma unroll
    for (int ct = 0; ct < 8; ++ct) acc[ct] = (f32x4){0.f, 0.f, 0.f, 0.f};

    __syncthreads();

#pragma unroll
    for (int kk = 0; kk < 4; ++kk) {
#pragma unroll
        for (int ct = 0; ct < 8; ++ct) {
            const int fo = ((ct * 4 + kk) * 64 + lane) * 8;
            bf16x8 bhi = *(const bf16x8*)&wlds[fo];
            bf16x8 blo = *(const bf16x8*)&wlds[16384 + fo];
            acc[ct] = __builtin_amdgcn_mfma_f32_16x16x32_bf16(ahi[kk], bhi, acc[ct], 0, 0, 0);
            acc[ct] = __builtin_amdgcn_mfma_f32_16x16x32_bf16(ahi[kk], blo, acc[ct], 0, 0, 0);
            acc[ct] = __builtin_amdgcn_mfma_f32_16x16x32_bf16(alo[kk], bhi, acc[ct], 0, 0, 0);
        }
    }

    float ps[4][H], pd[4][H];
#pragma unroll
    for (int r = 0; r < 4; ++r)
#pragma unroll
        for (int h = 0; h < H; ++h) { ps[r][h] = 0.f; pd[r][h] = 0.f; }

#pragma unroll
    for (int ct = 0; ct < 8; ++ct) {
        float as_c = att_s[ct * 16 + lr];
        float ad_c = att_d[ct * 16 + lr];
        const int h = (ct * H) >> 3;
#pragma unroll
        for (int r = 0; r < 4; ++r) {
            float v = acc[ct][r];
            int row = row0 + lk * 4 + r;
            if (row < N) hb[(size_t)row * 128 + ct * 16 + lr] = f2bf(v);
            ps[r][h] += v * as_c;
            pd[r][h] += v * ad_c;
        }
    }

#pragma unroll
    for (int m = 1; m < 16; m <<= 1) {
#pragma unroll
        for (int r = 0; r < 4; ++r)
#pragma unroll
            for (int h = 0; h < H; ++h) {
                ps[r][h] += __shfl_xor(ps[r][h], m);
                pd[r][h] += __shfl_xor(pd[r][h], m);
            }
    }
    if (lr == 0) {
#pragma unroll
        for (int r = 0; r < 4; ++r) {
            int row = row0 + lk * 4 + r;
            if (row < N) {
                if (H == 4) {
                    *(float4*)&a_s[(size_t)row * 4] =
                        make_float4(ps[r][0], ps[r][1], ps[r][2], ps[r][3]);
                    *(float4*)&a_d[(size_t)row * 4] =
                        make_float4(pd[r][0], pd[r][1], pd[r][2], pd[r][3]);
                } else {
                    a_s[row] = ps[r][0];
                    a_d[row] = pd[r][0];
                }
            }
        }
    }
}

// ---------------------------------------------------------------------------
// per-edge softmax numerator p = exp(leaky_relu(a_s[src]+a_d[dst]))
// ---------------------------------------------------------------------------
__global__ void pk4_kernel(const int* __restrict__ csr_src, const int* __restrict__ csr_dst,
                           const float* __restrict__ a_s, const float* __restrict__ a_d,
                           float* __restrict__ pbuf, int E) {
    int i = blockIdx.x * blockDim.x + threadIdx.x;
    if (i >= E) return;
    int s = csr_src[i], d = csr_dst[i];
    const float4 as4 = *(const float4*)&a_s[(size_t)s * 4];
    const float4 ad4 = *(const float4*)&a_d[(size_t)d * 4];
    float4 o;
    float lg;
    lg = as4.x + ad4.x; lg = lg >= 0.f ? lg : NEG_SLOPE * lg; o.x = expf(lg);
    lg = as4.y + ad4.y; lg = lg >= 0.f ? lg : NEG_SLOPE * lg; o.y = expf(lg);
    lg = as4.z + ad4.z; lg = lg >= 0.f ? lg : NEG_SLOPE * lg; o.z = expf(lg);
    lg = as4.w + ad4.w; lg = lg >= 0.f ? lg : NEG_SLOPE * lg; o.w = expf(lg);
    *(float4*)&pbuf[(size_t)i * 4] = o;
}

__global__ void pk1_kernel(const int* __restrict__ csr_src, const int* __restrict__ csr_dst,
                           const float* __restrict__ a_s, const float* __restrict__ a_d,
                           float* __restrict__ pbuf, int E) {
    int i = blockIdx.x * blockDim.x + threadIdx.x;
    if (i >= E) return;
    float lg = a_s[csr_src[i]] + a_d[csr_dst[i]];
    lg = lg >= 0.f ? lg : NEG_SLOPE * lg;
    pbuf[i] = expf(lg);
}

// ---------------------------------------------------------------------------
// aggregation + bias + ELU + residual + LayerNorm.  One wave per node.
// ---------------------------------------------------------------------------
template <int H, bool RES>
__global__ __launch_bounds__(256) void agg_kernel(const unsigned short* __restrict__ hb,
                                                  const float* __restrict__ pbuf,
                                                  const int* __restrict__ off,
                                                  const int* __restrict__ csr_src,
                                                  const float* __restrict__ xprev,
                                                  const float* __restrict__ bias,
                                                  const float* __restrict__ ln_g,
                                                  const float* __restrict__ ln_b,
                                                  float* __restrict__ xout, int N) {
    const int lane = threadIdx.x & 63;
    const int n = blockIdx.x * 4 + (threadIdx.x >> 6);
    if (n >= N) return;
    const int c2 = lane * 2;
    const int head = (c2 * H) >> 7;
    const int base = off[n];
    const int deg = off[n + 1] - base;

    float a0 = 0.f, a1 = 0.f;
    float b0 = 0.f, b1 = 0.f;
    float c0 = 0.f, c1 = 0.f;
    float d0 = 0.f, d1 = 0.f;
    float psum = 0.f;

    for (int e0 = 0; e0 < deg; e0 += 64) {
        const int ce = min(64, deg - e0);
        int myidx = 0;
        if (lane < ce) myidx = csr_src[base + e0 + lane];
        const float* pb = &pbuf[(size_t)(base + e0) * H + head];
        int e = 0;
        for (; e + 3 < ce; e += 4) {
            int s0 = __shfl(myidx, e);
            int s1 = __shfl(myidx, e + 1);
            int s2 = __shfl(myidx, e + 2);
            int s3 = __shfl(myidx, e + 3);
            float p0 = pb[(size_t)(e + 0) * H];
            float p1 = pb[(size_t)(e + 1) * H];
            float p2 = pb[(size_t)(e + 2) * H];
            float p3 = pb[(size_t)(e + 3) * H];
            unsigned hv0 = *(const unsigned*)&hb[((size_t)s0 << 7) + c2];
            unsigned hv1 = *(const unsigned*)&hb[((size_t)s1 << 7) + c2];
            unsigned hv2 = *(const unsigned*)&hb[((size_t)s2 << 7) + c2];
            unsigned hv3 = *(const unsigned*)&hb[((size_t)s3 << 7) + c2];
            psum += (p0 + p1) + (p2 + p3);
            a0 = fmaf(p0, bf2f((unsigned short)hv0), a0);
            a1 = fmaf(p0, bf2f((unsigned short)(hv0 >> 16)), a1);
            b0 = fmaf(p1, bf2f((unsigned short)hv1), b0);
            b1 = fmaf(p1, bf2f((unsigned short)(hv1 >> 16)), b1);
            c0 = fmaf(p2, bf2f((unsigned short)hv2), c0);
            c1 = fmaf(p2, bf2f((unsigned short)(hv2 >> 16)), c1);
            d0 = fmaf(p3, bf2f((unsigned short)hv3), d0);
            d1 = fmaf(p3, bf2f((unsigned short)(hv3 >> 16)), d1);
        }
        for (; e < ce; ++e) {
            int s0 = __shfl(myidx, e);
            float p0 = pb[(size_t)e * H];
            unsigned hv0 = *(const unsigned*)&hb[((size_t)s0 << 7) + c2];
            psum += p0;
            a0 = fmaf(p0, bf2f((unsigned short)hv0), a0);
            a1 = fmaf(p0, bf2f((unsigned short)(hv0 >> 16)), a1);
        }
    }
    a0 = (a0 + b0) + (c0 + d0);
    a1 = (a1 + b1) + (c1 + d1);

    float inv = 1.0f / (psum + 1e-16f);
    float acc0 = a0 * inv + bias[c2];
    float acc1 = a1 * inv + bias[c2 + 1];
    acc0 = acc0 > 0.f ? acc0 : (expf(acc0) - 1.0f);
    acc1 = acc1 > 0.f ? acc1 : (expf(acc1) - 1.0f);
    if (RES) {
        float2 xp = *(const float2*)&xprev[((size_t)n << 7) + c2];
        acc0 += xp.x;
        acc1 += xp.y;
    }

    float s1v = acc0 + acc1;
    float s2v = acc0 * acc0 + acc1 * acc1;
#pragma unroll
    for (int m = 1; m < 64; m <<= 1) {
        s1v += __shfl_xor(s1v, m);
        s2v += __shfl_xor(s2v, m);
    }
    float mu = s1v * (1.0f / 128.0f);
    float var = s2v * (1.0f / 128.0f) - mu * mu;
    float rstd = rsqrtf(var + 1e-5f);
    float2 o;
    o.x = (acc0 - mu) * rstd * ln_g[c2] + ln_b[c2];
    o.y = (acc1 - mu) * rstd * ln_g[c2 + 1] + ln_b[c2 + 1];
    *(float2*)&xout[((size_t)n << 7) + c2] = o;
}

// ---------------------------------------------------------------------------
// MFMA prediction MLP.  4 waves/block, 16 rows/wave, 64 rows/block.
// Weights (bf16-hi fragments) staged in LDS; activations split-bf16 (L1).
// L1: 256->128 (128 MFMA/wave), h1 -> padded LDS, L2: 128->64 (16 MFMA),
// L3: dot(64) + sigmoid in registers.
// ---------------------------------------------------------------------------
__global__ __launch_bounds__(256) void mlp_mfma_kernel(const float* __restrict__ x,
                                                       const int* __restrict__ uidx,
                                                       const int* __restrict__ vidx,
                                                       int num_users,
                                                       const unsigned short* __restrict__ w1f,
                                                       const float* __restrict__ mb1,
                                                       const unsigned short* __restrict__ w2f,
                                                       const float* __restrict__ mb2,
                                                       const float* __restrict__ mw3,
                                                       const float* __restrict__ mb3,
                                                       float* __restrict__ out, int B) {
    __shared__ unsigned short w1s[32768];       // 64 KB
    __shared__ unsigned short w2s[8192];        // 16 KB
    __shared__ unsigned short h1s[4][16 * 136]; // padded rows (2-way banks), 17.4 KB
    const int t = threadIdx.x;
    const int lane = t & 63;
    const int wave = t >> 6;
    const int row0 = blockIdx.x * 64 + wave * 16;
    const int lr = lane & 15;
    const int lk = lane >> 4;

    // stage weight fragments
    for (int i = t; i < 4096; i += 256) ((int4*)w1s)[i] = ((const int4*)w1f)[i];
    for (int i = t; i < 1024; i += 256) ((int4*)w2s)[i] = ((const int4*)w2f)[i];

    // A fragments for layer 1 (row = row0+lr, k 0..255 = user|item), split hi/lo
    int b = row0 + lr;
    if (b >= B) b = B - 1;  // clamp; padded rows never stored
    const float* urow = &x[(size_t)uidx[b] * 128];
    const float* vrow = &x[(size_t)(vidx[b] + num_users) * 128];
    bf16x8 ahi[8], alo[8];
#pragma unroll
    for (int kk = 0; kk < 8; ++kk) {
        const float* ap = (kk < 4) ? &urow[kk * 32 + lk * 8] : &vrow[(kk - 4) * 32 + lk * 8];
        float4 v0 = *(const float4*)ap;
        float4 v1 = *(const float4*)(ap + 4);
        float f[8] = {v0.x, v0.y, v0.z, v0.w, v1.x, v1.y, v1.z, v1.w};
#pragma unroll
        for (int j = 0; j < 8; ++j) {
            unsigned short hi = f2bf(f[j]);
            unsigned short lo = f2bf(f[j] - bf2f(hi));
            ((short*)&ahi[kk])[j] = (short)hi;
            ((short*)&alo[kk])[j] = (short)lo;
        }
    }

    f32x4 acc[8];
#pragma unroll
    for (int ct = 0; ct < 8; ++ct) acc[ct] = (f32x4){0.f, 0.f, 0.f, 0.f};

    __syncthreads();

    // ---- layer 1 MFMAs: K=256 (8 chunks), C=128 (8 col tiles) ----
#pragma unroll
    for (int kk = 0; kk < 8; ++kk) {
#pragma unroll
        for (int ct = 0; ct < 8; ++ct) {
            const int fo = ((ct * 8 + kk) * 64 + lane) * 8;
            bf16x8 bhi = *(const bf16x8*)&w1s[fo];
            acc[ct] = __builtin_amdgcn_mfma_f32_16x16x32_bf16(ahi[kk], bhi, acc[ct], 0, 0, 0);
            acc[ct] = __builtin_amdgcn_mfma_f32_16x16x32_bf16(alo[kk], bhi, acc[ct], 0, 0, 0);
        }
    }

    // bias + relu -> h1 LDS (row-major, padded to 136)
#pragma unroll
    for (int ct = 0; ct < 8; ++ct) {
        const int col = ct * 16 + lr;
        const float b1 = mb1[col];
#pragma unroll
        for (int r = 0; r < 4; ++r) {
            float v = fmaxf(acc[ct][r] + b1, 0.f);
            h1s[wave][(lk * 4 + r) * 136 + col] = f2bf(v);
        }
    }
    __syncthreads();

    // ---- layer 2: A frags from h1s (row=lr, k = kk*32+lk*8+j) ----
    bf16x8 a2[4];
#pragma unroll
    for (int kk = 0; kk < 4; ++kk)
        a2[kk] = *(const bf16x8*)&h1s[wave][lr * 136 + kk * 32 + lk * 8];

    f32x4 acc2[4];
#pragma unroll
    for (int ct = 0; ct < 4; ++ct) acc2[ct] = (f32x4){0.f, 0.f, 0.f, 0.f};
#pragma unroll
    for (int kk = 0; kk < 4; ++kk) {
#pragma unroll
        for (int ct = 0; ct < 4; ++ct) {
            const int fo = ((ct * 4 + kk) * 64 + lane) * 8;
            bf16x8 bhi = *(const bf16x8*)&w2s[fo];
            acc2[ct] = __builtin_amdgcn_mfma_f32_16x16x32_bf16(a2[kk], bhi, acc2[ct], 0, 0, 0);
        }
    }

    // ---- layer 3: bias+relu then dot with mw3, butterfly over 16 col-lanes ----
    float s[4] = {0.f, 0.f, 0.f, 0.f};
#pragma unroll
    for (int ct = 0; ct < 4; ++ct) {
        const int col = ct * 16 + lr;
        const float b2 = mb2[col];
        const float w3 = mw3[col];
#pragma unroll
        for (int r = 0; r < 4; ++r) {
            float v = fmaxf(acc2[ct][r] + b2, 0.f);
            s[r] = fmaf(v, w3, s[r]);
        }
    }
#pragma unroll
    for (int m = 1; m < 16; m <<= 1) {
#pragma unroll
        for (int r = 0; r < 4; ++r) s[r] += __shfl_xor(s[r], m);
    }
    if (lr == 0) {
        const float b3 = mb3[0];
#pragma unroll
        for (int r = 0; r < 4; ++r) {
            int row = row0 + lk * 4 + r;
            if (row < B) out[row] = 1.0f / (1.0f + expf(-(s[r] + b3)));
        }
    }
}

// ---------------------------------------------------------------------------
// launcher
// ---------------------------------------------------------------------------
extern "C" void kernel_launch(void* const* d_in, const int* in_sizes, int n_in,
                              void* d_out, int out_size, void* d_ws, size_t ws_size,
                              hipStream_t stream) {
    const int* uidx = (const int*)d_in[0];
    const int* vidx = (const int*)d_in[1];
    const int* eidx = (const int*)d_in[2];
    const float* utab = (const float*)d_in[3];
    const float* itab = (const float*)d_in[4];
    const float* W0 = (const float*)d_in[5];
    const float* as0 = (const float*)d_in[6];
    const float* ad0 = (const float*)d_in[7];
    const float* bb0 = (const float*)d_in[8];
    const float* W1 = (const float*)d_in[9];
    const float* as1 = (const float*)d_in[10];
    const float* ad1 = (const float*)d_in[11];
    const float* bb1 = (const float*)d_in[12];
    const float* W2 = (const float*)d_in[13];
    const float* as2 = (const float*)d_in[14];
    const float* ad2 = (const float*)d_in[15];
    const float* bb2 = (const float*)d_in[16];
    const float* ln_g = (const float*)d_in[17];
    const float* ln_b = (const float*)d_in[18];
    const float* mw1 = (const float*)d_in[19];
    const float* mb1 = (const float*)d_in[20];
    const float* mw2 = (const float*)d_in[21];
    const float* mb2 = (const float*)d_in[22];
    const float* mw3 = (const float*)d_in[23];
    const float* mb3 = (const float*)d_in[24];

    const int B = in_sizes[0];
    const int E = in_sizes[2] / 2;
    const int num_users = in_sizes[3] / D128;
    const int num_items = in_sizes[4] / D128;
    const int N = num_users + num_items;
    const int* esrc = eidx;
    const int* edst = eidx + E;

    size_t wsoff = 0;
    auto alloc = [&](size_t bytes) {
        void* p = (char*)d_ws + wsoff;
        wsoff += (bytes + 255) & ~(size_t)255;
        return p;
    };
    float* bufA = (float*)alloc((size_t)N * 128 * 4);
    float* bufB = (float*)alloc((size_t)N * 128 * 4);
    unsigned short* hb = (unsigned short*)alloc((size_t)N * 128 * 2);
    float* aS = (float*)alloc((size_t)N * 4 * 4);
    float* aD = (float*)alloc((size_t)N * 4 * 4);
    float* pbuf = (float*)alloc((size_t)E * 4 * 4);
    int* cnt = (int*)alloc((size_t)(N + 1) * 4);
    int* off = (int*)alloc((size_t)(N + 1) * 4);
    int* cur = (int*)alloc((size_t)(N + 1) * 4);
    int* csr_src = (int*)alloc((size_t)E * 4);
    int* csr_dst = (int*)alloc((size_t)E * 4);
    int* partials = (int*)alloc(64 * 4);
    int* pp = (int*)alloc(64 * 4);
    unsigned short* wb0 = (unsigned short*)alloc(2 * 16384 * 2);
    unsigned short* wb1 = (unsigned short*)alloc(2 * 16384 * 2);
    unsigned short* wb2 = (unsigned short*)alloc(2 * 16384 * 2);
    unsigned short* w1f = (unsigned short*)alloc(32768 * 2);
    unsigned short* w2f = (unsigned short*)alloc(8192 * 2);
    (void)ws_size;

    wrepack_kernel<<<64, 256, 0, stream>>>(W0, wb0);
    wrepack_kernel<<<64, 256, 0, stream>>>(W1, wb1);
    wrepack_kernel<<<64, 256, 0, stream>>>(W2, wb2);
    wrepack_bf16_kernel<<<128, 256, 0, stream>>>(mw1, w1f, 256, 128);
    wrepack_bf16_kernel<<<32, 256, 0, stream>>>(mw2, w2f, 128, 64);

    const int NB = (N + SCAN_CHUNK - 1) / SCAN_CHUNK;
    zero_int_kernel<<<(N + 255) / 256, 256, 0, stream>>>(cnt, N);
    count_kernel<<<(E + 255) / 256, 256, 0, stream>>>(edst, E, cnt);
    scan_local_kernel<<<NB, SB, 0, stream>>>(cnt, off, partials, N);
    scan_partials_kernel<<<1, 64, 0, stream>>>(partials, pp, NB, off, N);
    scan_add_kernel<<<(N + 255) / 256, 256, 0, stream>>>(off, cur, pp, N);
    fill_kernel<<<(E + 255) / 256, 256, 0, stream>>>(esrc, edst, E, cur, csr_src, csr_dst);

    const int gemm_grid = (N + 127) / 128;
    const int egrid = (E + 255) / 256;
    const int agrid = (N + 3) / 4;

    // ---- layer 0 (H=4, no residual; X = virtual concat of tables) ----
    gemm_mfma_kernel<4, true><<<gemm_grid, 512, 0, stream>>>(utab, itab, num_users, wb0, as0,
                                                             ad0, hb, aS, aD, N);
    pk4_kernel<<<egrid, 256, 0, stream>>>(csr_src, csr_dst, aS, aD, pbuf, E);
    agg_kernel<4, false><<<agrid, 256, 0, stream>>>(hb, pbuf, off, csr_src, nullptr, bb0, ln_g,
                                                    ln_b, bufB, N);
    // ---- layer 1 (H=4, residual) ----
    gemm_mfma_kernel<4, false><<<gemm_grid, 512, 0, stream>>>(bufB, nullptr, 0, wb1, as1, ad1,
                                                              hb, aS, aD, N);
    pk4_kernel<<<egrid, 256, 0, stream>>>(csr_src, csr_dst, aS, aD, pbuf, E);
    agg_kernel<4, true><<<agrid, 256, 0, stream>>>(hb, pbuf, off, csr_src, bufB, bb1, ln_g,
                                                   ln_b, bufA, N);
    // ---- layer 2 (H=1, residual) ----
    gemm_mfma_kernel<1, false><<<gemm_grid, 512, 0, stream>>>(bufA, nullptr, 0, wb2, as2, ad2,
                                                              hb, aS, aD, N);
    pk1_kernel<<<egrid, 256, 0, stream>>>(csr_src, csr_dst, aS, aD, pbuf, E);
    agg_kernel<1, true><<<agrid, 256, 0, stream>>>(hb, pbuf, off, csr_src, bufA, bb2, ln_g,
                                                   ln_b, bufB, N);

    // ---- prediction MLP (MFMA) ----
    mlp_mfma_kernel<<<(B + 63) / 64, 256, 0, stream>>>(bufB, uidx, vidx, num_users, w1f, mb1,
                                                       w2f, mb2, mw3, mb3, (float*)d_out, B);
}

// Round 11
// 251.155 us; speedup vs baseline: 1.9304x; 1.1055x over previous
//
#include <hip/hip_runtime.h>
#include <hip/hip_bf16.h>

#define D128 128
#define NEG_SLOPE 0.2f

typedef __attribute__((ext_vector_type(8))) short bf16x8;
typedef __attribute__((ext_vector_type(4))) float f32x4;

__device__ inline float bf2f(unsigned short u) {
    return __uint_as_float(((unsigned)u) << 16);
}
__device__ inline unsigned short f2bf(float f) {  // RTNE
    unsigned u = __float_as_uint(f);
    unsigned r = (u + 0x7fffu + ((u >> 16) & 1u)) >> 16;
    return (unsigned short)r;
}

// ---------------------------------------------------------------------------
// CSR build
// ---------------------------------------------------------------------------
__global__ void zero_int_kernel(int* __restrict__ p, int n) {
    int i = blockIdx.x * blockDim.x + threadIdx.x;
    if (i < n) p[i] = 0;
}

__global__ void count_kernel(const int* __restrict__ dst, int E, int* __restrict__ cnt) {
    int e = blockIdx.x * blockDim.x + threadIdx.x;
    if (e < E) atomicAdd(&cnt[dst[e]], 1);
}

#define SB 256
#define SCAN_CHUNK 2048  // SB * 8

__global__ __launch_bounds__(SB) void scan_local_kernel(const int* __restrict__ cnt,
                                                        int* __restrict__ off,
                                                        int* __restrict__ partials, int N) {
    __shared__ int lds[SB];
    const int b = blockIdx.x;
    const int t = threadIdx.x;
    const int base = b * SCAN_CHUNK + t * 8;
    int v[8];
    int s = 0;
#pragma unroll
    for (int j = 0; j < 8; ++j) {
        int i = base + j;
        v[j] = (i < N) ? cnt[i] : 0;
        s += v[j];
    }
    lds[t] = s;
    __syncthreads();
    for (int d = 1; d < SB; d <<= 1) {
        int y = (t >= d) ? lds[t - d] : 0;
        __syncthreads();
        lds[t] += y;
        __syncthreads();
    }
    int pref = lds[t] - s;
#pragma unroll
    for (int j = 0; j < 8; ++j) {
        int i = base + j;
        if (i < N) off[i] = pref;
        pref += v[j];
    }
    if (t == SB - 1) partials[b] = lds[t];
}

__global__ __launch_bounds__(64) void scan_partials_kernel(int* __restrict__ partials,
                                                           int* __restrict__ pp, int NB,
                                                           int* __restrict__ off, int N) {
    __shared__ int lds[64];
    int t = threadIdx.x;
    int v = (t < NB) ? partials[t] : 0;
    lds[t] = v;
    __syncthreads();
    for (int d = 1; d < 64; d <<= 1) {
        int y = (t >= d) ? lds[t - d] : 0;
        __syncthreads();
        lds[t] += y;
        __syncthreads();
    }
    pp[t] = lds[t] - v;
    if (t == 63) off[N] = lds[63];
}

__global__ void scan_add_kernel(int* __restrict__ off, int* __restrict__ cur,
                                const int* __restrict__ pp, int N) {
    int i = blockIdx.x * blockDim.x + threadIdx.x;
    if (i < N) {
        int o = off[i] + pp[i / SCAN_CHUNK];
        off[i] = o;
        cur[i] = o;
    }
}

__global__ void fill_kernel(const int* __restrict__ src, const int* __restrict__ dst, int E,
                            int* __restrict__ cur, int* __restrict__ csr_src,
                            int* __restrict__ csr_dst) {
    int e = blockIdx.x * blockDim.x + threadIdx.x;
    if (e < E) {
        int d = dst[e];
        int p = atomicAdd(&cur[d], 1);
        csr_src[p] = src[e];
        csr_dst[p] = d;
    }
}

// ---------------------------------------------------------------------------
// W repack into MFMA B-fragment order, split hi/lo bf16 — all 3 GAT layers
// in one dispatch (blockIdx.y selects the weight matrix).
// ---------------------------------------------------------------------------
__global__ __launch_bounds__(256) void wrepack3_kernel(const float* __restrict__ W0,
                                                       const float* __restrict__ W1,
                                                       const float* __restrict__ W2,
                                                       unsigned short* __restrict__ wb0,
                                                       unsigned short* __restrict__ wb1,
                                                       unsigned short* __restrict__ wb2) {
    const float* W = (blockIdx.y == 0) ? W0 : (blockIdx.y == 1) ? W1 : W2;
    unsigned short* Wb = (blockIdx.y == 0) ? wb0 : (blockIdx.y == 1) ? wb1 : wb2;
    int i = blockIdx.x * 256 + threadIdx.x;  // 0..16383
    if (i >= 16384) return;
    int j = i & 7;
    int l = (i >> 3) & 63;
    int kk = (i >> 9) & 3;
    int ct = i >> 11;
    int k = kk * 32 + ((l >> 4) & 3) * 8 + j;
    int c = ct * 16 + (l & 15);
    float w = W[k * 128 + c];
    unsigned short hi = f2bf(w);
    unsigned short lo = f2bf(w - bf2f(hi));
    Wb[i] = hi;
    Wb[16384 + i] = lo;
}

// bf16-hi-only repack for the two MLP weights in one dispatch.
__global__ __launch_bounds__(256) void wrepack_mlp_kernel(const float* __restrict__ mw1,
                                                          unsigned short* __restrict__ w1f,
                                                          const float* __restrict__ mw2,
                                                          unsigned short* __restrict__ w2f) {
    const int y = blockIdx.y;
    const float* W = y ? mw2 : mw1;
    unsigned short* Wf = y ? w2f : w1f;
    const int K = y ? 128 : 256, C = y ? 64 : 128;
    int total = K * C;
    int i = blockIdx.x * 256 + threadIdx.x;
    if (i >= total) return;
    int j = i & 7;
    int l = (i >> 3) & 63;
    int kkct = i >> 9;
    int KK = K >> 5;
    int kk = kkct % KK;
    int ct = kkct / KK;
    int k = kk * 32 + (l >> 4) * 8 + j;
    int c = ct * 16 + (l & 15);
    Wf[i] = f2bf(W[k * C + c]);
}

// ---------------------------------------------------------------------------
// MFMA GEMM (split-bf16 ~ fp32 accuracy) fused with attention scalars.
// 8 waves/block, 128 rows/block, W fragments staged in LDS.
// ---------------------------------------------------------------------------
template <int H, bool SPLIT>
__global__ __launch_bounds__(512) void gemm_mfma_kernel(const float* __restrict__ X0,
                                                        const float* __restrict__ X1, int split,
                                                        const unsigned short* __restrict__ Wb,
                                                        const float* __restrict__ att_s,
                                                        const float* __restrict__ att_d,
                                                        unsigned short* __restrict__ hb,
                                                        float* __restrict__ a_s,
                                                        float* __restrict__ a_d, int N) {
    __shared__ unsigned short wlds[32768];  // 64 KB: hi [0,16384), lo [16384,32768)
    const int t = threadIdx.x;
    const int lane = t & 63;
    const int wave = t >> 6;
    const int row0 = blockIdx.x * 128 + wave * 16;

    for (int i = t; i < 4096; i += 512)
        ((int4*)wlds)[i] = ((const int4*)Wb)[i];

    const int lr = lane & 15;
    const int lk = lane >> 4;

    int arow = row0 + lr;
    if (arow >= N) arow = N - 1;  // clamp; padded rows never stored
    const float* xrow;
    if (SPLIT)
        xrow = (arow < split) ? &X0[(size_t)arow * 128] : &X1[(size_t)(arow - split) * 128];
    else
        xrow = &X0[(size_t)arow * 128];

    bf16x8 ahi[4], alo[4];
#pragma unroll
    for (int kk = 0; kk < 4; ++kk) {
        const float* ap = &xrow[kk * 32 + lk * 8];
        float4 v0 = *(const float4*)ap;
        float4 v1 = *(const float4*)(ap + 4);
        float f[8] = {v0.x, v0.y, v0.z, v0.w, v1.x, v1.y, v1.z, v1.w};
#pragma unroll
        for (int j = 0; j < 8; ++j) {
            unsigned short hi = f2bf(f[j]);
            unsigned short lo = f2bf(f[j] - bf2f(hi));
            ((short*)&ahi[kk])[j] = (short)hi;
            ((short*)&alo[kk])[j] = (short)lo;
        }
    }

    f32x4 acc[8];
#pragma unroll
    for (int ct = 0; ct < 8; ++ct) acc[ct] = (f32x4){0.f, 0.f, 0.f, 0.f};

    __syncthreads();

#pragma unroll
    for (int kk = 0; kk < 4; ++kk) {
#pragma unroll
        for (int ct = 0; ct < 8; ++ct) {
            const int fo = ((ct * 4 + kk) * 64 + lane) * 8;
            bf16x8 bhi = *(const bf16x8*)&wlds[fo];
            bf16x8 blo = *(const bf16x8*)&wlds[16384 + fo];
            acc[ct] = __builtin_amdgcn_mfma_f32_16x16x32_bf16(ahi[kk], bhi, acc[ct], 0, 0, 0);
            acc[ct] = __builtin_amdgcn_mfma_f32_16x16x32_bf16(ahi[kk], blo, acc[ct], 0, 0, 0);
            acc[ct] = __builtin_amdgcn_mfma_f32_16x16x32_bf16(alo[kk], bhi, acc[ct], 0, 0, 0);
        }
    }

    float ps[4][H], pd[4][H];
#pragma unroll
    for (int r = 0; r < 4; ++r)
#pragma unroll
        for (int h = 0; h < H; ++h) { ps[r][h] = 0.f; pd[r][h] = 0.f; }

#pragma unroll
    for (int ct = 0; ct < 8; ++ct) {
        float as_c = att_s[ct * 16 + lr];
        float ad_c = att_d[ct * 16 + lr];
        const int h = (ct * H) >> 3;
#pragma unroll
        for (int r = 0; r < 4; ++r) {
            float v = acc[ct][r];
            int row = row0 + lk * 4 + r;
            if (row < N) hb[(size_t)row * 128 + ct * 16 + lr] = f2bf(v);
            ps[r][h] += v * as_c;
            pd[r][h] += v * ad_c;
        }
    }

#pragma unroll
    for (int m = 1; m < 16; m <<= 1) {
#pragma unroll
        for (int r = 0; r < 4; ++r)
#pragma unroll
            for (int h = 0; h < H; ++h) {
                ps[r][h] += __shfl_xor(ps[r][h], m);
                pd[r][h] += __shfl_xor(pd[r][h], m);
            }
    }
    if (lr == 0) {
#pragma unroll
        for (int r = 0; r < 4; ++r) {
            int row = row0 + lk * 4 + r;
            if (row < N) {
                if (H == 4) {
                    *(float4*)&a_s[(size_t)row * 4] =
                        make_float4(ps[r][0], ps[r][1], ps[r][2], ps[r][3]);
                    *(float4*)&a_d[(size_t)row * 4] =
                        make_float4(pd[r][0], pd[r][1], pd[r][2], pd[r][3]);
                } else {
                    a_s[row] = ps[r][0];
                    a_d[row] = pd[r][0];
                }
            }
        }
    }
}

// ---------------------------------------------------------------------------
// per-edge softmax numerator p = exp(leaky_relu(a_s[src]+a_d[dst]))
// ---------------------------------------------------------------------------
__global__ void pk4_kernel(const int* __restrict__ csr_src, const int* __restrict__ csr_dst,
                           const float* __restrict__ a_s, const float* __restrict__ a_d,
                           float* __restrict__ pbuf, int E) {
    int i = blockIdx.x * blockDim.x + threadIdx.x;
    if (i >= E) return;
    int s = csr_src[i], d = csr_dst[i];
    const float4 as4 = *(const float4*)&a_s[(size_t)s * 4];
    const float4 ad4 = *(const float4*)&a_d[(size_t)d * 4];
    float4 o;
    float lg;
    lg = as4.x + ad4.x; lg = lg >= 0.f ? lg : NEG_SLOPE * lg; o.x = expf(lg);
    lg = as4.y + ad4.y; lg = lg >= 0.f ? lg : NEG_SLOPE * lg; o.y = expf(lg);
    lg = as4.z + ad4.z; lg = lg >= 0.f ? lg : NEG_SLOPE * lg; o.z = expf(lg);
    lg = as4.w + ad4.w; lg = lg >= 0.f ? lg : NEG_SLOPE * lg; o.w = expf(lg);
    *(float4*)&pbuf[(size_t)i * 4] = o;
}

__global__ void pk1_kernel(const int* __restrict__ csr_src, const int* __restrict__ csr_dst,
                           const float* __restrict__ a_s, const float* __restrict__ a_d,
                           float* __restrict__ pbuf, int E) {
    int i = blockIdx.x * blockDim.x + threadIdx.x;
    if (i >= E) return;
    float lg = a_s[csr_src[i]] + a_d[csr_dst[i]];
    lg = lg >= 0.f ? lg : NEG_SLOPE * lg;
    pbuf[i] = expf(lg);
}

// ---------------------------------------------------------------------------
// aggregation + bias + ELU + residual + LayerNorm.
// CHANNEL-SPLIT: 16 lanes per node (8 channels each, dwordx4 gathers),
// 4 nodes per wave, 16 nodes per 256-thr block.  2-way edge unroll ->
// up to 8 independent 256B row-gathers in flight per wave.  No LDS.
// ---------------------------------------------------------------------------
template <int H, bool RES>
__global__ __launch_bounds__(256) void agg_kernel(const unsigned short* __restrict__ hb,
                                                  const float* __restrict__ pbuf,
                                                  const int* __restrict__ off,
                                                  const int* __restrict__ csr_src,
                                                  const float* __restrict__ xprev,
                                                  const float* __restrict__ bias,
                                                  const float* __restrict__ ln_g,
                                                  const float* __restrict__ ln_b,
                                                  float* __restrict__ xout, int N) {
    const int t = threadIdx.x;
    const int l16 = t & 15;                 // lane within node group
    const int gbase = t & 48;               // group's base lane within wave
    const int n = blockIdx.x * 16 + (t >> 4);
    if (n >= N) return;
    const int c8 = l16 * 8;                 // first of this lane's 8 channels
    const int head = (c8 * H) >> 7;         // c8 / (128/H)
    const int base = off[n];
    const int deg = off[n + 1] - base;

    float accA[8], accB[8];
#pragma unroll
    for (int j = 0; j < 8; ++j) { accA[j] = 0.f; accB[j] = 0.f; }
    float psA = 0.f, psB = 0.f;

    for (int e0 = 0; e0 < deg; e0 += 16) {
        const int ce = min(16, deg - e0);
        int myidx = 0;
        if (l16 < ce) myidx = csr_src[base + e0 + l16];
        const float* pb = &pbuf[(size_t)(base + e0) * H + head];
        int e = 0;
        for (; e + 1 < ce; e += 2) {
            int s0 = __shfl(myidx, gbase + e);
            int s1 = __shfl(myidx, gbase + e + 1);
            float p0 = pb[(size_t)e * H];
            float p1 = pb[(size_t)(e + 1) * H];
            uint4 h0 = *(const uint4*)&hb[((size_t)s0 << 7) + c8];
            uint4 h1 = *(const uint4*)&hb[((size_t)s1 << 7) + c8];
            psA += p0;
            psB += p1;
            accA[0] = fmaf(p0, bf2f((unsigned short)h0.x), accA[0]);
            accA[1] = fmaf(p0, bf2f((unsigned short)(h0.x >> 16)), accA[1]);
            accA[2] = fmaf(p0, bf2f((unsigned short)h0.y), accA[2]);
            accA[3] = fmaf(p0, bf2f((unsigned short)(h0.y >> 16)), accA[3]);
            accA[4] = fmaf(p0, bf2f((unsigned short)h0.z), accA[4]);
            accA[5] = fmaf(p0, bf2f((unsigned short)(h0.z >> 16)), accA[5]);
            accA[6] = fmaf(p0, bf2f((unsigned short)h0.w), accA[6]);
            accA[7] = fmaf(p0, bf2f((unsigned short)(h0.w >> 16)), accA[7]);
            accB[0] = fmaf(p1, bf2f((unsigned short)h1.x), accB[0]);
            accB[1] = fmaf(p1, bf2f((unsigned short)(h1.x >> 16)), accB[1]);
            accB[2] = fmaf(p1, bf2f((unsigned short)h1.y), accB[2]);
            accB[3] = fmaf(p1, bf2f((unsigned short)(h1.y >> 16)), accB[3]);
            accB[4] = fmaf(p1, bf2f((unsigned short)h1.z), accB[4]);
            accB[5] = fmaf(p1, bf2f((unsigned short)(h1.z >> 16)), accB[5]);
            accB[6] = fmaf(p1, bf2f((unsigned short)h1.w), accB[6]);
            accB[7] = fmaf(p1, bf2f((unsigned short)(h1.w >> 16)), accB[7]);
        }
        if (e < ce) {
            int s0 = __shfl(myidx, gbase + e);
            float p0 = pb[(size_t)e * H];
            uint4 h0 = *(const uint4*)&hb[((size_t)s0 << 7) + c8];
            psA += p0;
            accA[0] = fmaf(p0, bf2f((unsigned short)h0.x), accA[0]);
            accA[1] = fmaf(p0, bf2f((unsigned short)(h0.x >> 16)), accA[1]);
            accA[2] = fmaf(p0, bf2f((unsigned short)h0.y), accA[2]);
            accA[3] = fmaf(p0, bf2f((unsigned short)(h0.y >> 16)), accA[3]);
            accA[4] = fmaf(p0, bf2f((unsigned short)h0.z), accA[4]);
            accA[5] = fmaf(p0, bf2f((unsigned short)(h0.z >> 16)), accA[5]);
            accA[6] = fmaf(p0, bf2f((unsigned short)h0.w), accA[6]);
            accA[7] = fmaf(p0, bf2f((unsigned short)(h0.w >> 16)), accA[7]);
        }
    }

    const float inv = 1.0f / (psA + psB + 1e-16f);
    float4 bi0 = *(const float4*)&bias[c8];
    float4 bi1 = *(const float4*)&bias[c8 + 4];
    float val[8];
#pragma unroll
    for (int j = 0; j < 8; ++j) {
        float bj = (j < 4) ? ((const float*)&bi0)[j] : ((const float*)&bi1)[j - 4];
        float v = (accA[j] + accB[j]) * inv + bj;
        val[j] = v > 0.f ? v : (expf(v) - 1.0f);
    }
    if (RES) {
        float4 x0 = *(const float4*)&xprev[((size_t)n << 7) + c8];
        float4 x1 = *(const float4*)&xprev[((size_t)n << 7) + c8 + 4];
        val[0] += x0.x; val[1] += x0.y; val[2] += x0.z; val[3] += x0.w;
        val[4] += x1.x; val[5] += x1.y; val[6] += x1.z; val[7] += x1.w;
    }

    float s1v = 0.f, s2v = 0.f;
#pragma unroll
    for (int j = 0; j < 8; ++j) { s1v += val[j]; s2v += val[j] * val[j]; }
#pragma unroll
    for (int m = 1; m < 16; m <<= 1) {
        s1v += __shfl_xor(s1v, m);
        s2v += __shfl_xor(s2v, m);
    }
    float mu = s1v * (1.0f / 128.0f);
    float var = s2v * (1.0f / 128.0f) - mu * mu;
    float rstd = rsqrtf(var + 1e-5f);
    float4 g0 = *(const float4*)&ln_g[c8];
    float4 g1 = *(const float4*)&ln_g[c8 + 4];
    float4 lb0 = *(const float4*)&ln_b[c8];
    float4 lb1 = *(const float4*)&ln_b[c8 + 4];
    float4 o0, o1;
    o0.x = (val[0] - mu) * rstd * g0.x + lb0.x;
    o0.y = (val[1] - mu) * rstd * g0.y + lb0.y;
    o0.z = (val[2] - mu) * rstd * g0.z + lb0.z;
    o0.w = (val[3] - mu) * rstd * g0.w + lb0.w;
    o1.x = (val[4] - mu) * rstd * g1.x + lb1.x;
    o1.y = (val[5] - mu) * rstd * g1.y + lb1.y;
    o1.z = (val[6] - mu) * rstd * g1.z + lb1.z;
    o1.w = (val[7] - mu) * rstd * g1.w + lb1.w;
    *(float4*)&xout[((size_t)n << 7) + c8] = o0;
    *(float4*)&xout[((size_t)n << 7) + c8 + 4] = o1;
}

// ---------------------------------------------------------------------------
// MFMA prediction MLP.  4 waves/block, 16 rows/wave, 64 rows/block.
// ---------------------------------------------------------------------------
__global__ __launch_bounds__(256) void mlp_mfma_kernel(const float* __restrict__ x,
                                                       const int* __restrict__ uidx,
                                                       const int* __restrict__ vidx,
                                                       int num_users,
                                                       const unsigned short* __restrict__ w1f,
                                                       const float* __restrict__ mb1,
                                                       const unsigned short* __restrict__ w2f,
                                                       const float* __restrict__ mb2,
                                                       const float* __restrict__ mw3,
                                                       const float* __restrict__ mb3,
                                                       float* __restrict__ out, int B) {
    __shared__ unsigned short w1s[32768];
    __shared__ unsigned short w2s[8192];
    __shared__ unsigned short h1s[4][16 * 136];
    const int t = threadIdx.x;
    const int lane = t & 63;
    const int wave = t >> 6;
    const int row0 = blockIdx.x * 64 + wave * 16;
    const int lr = lane & 15;
    const int lk = lane >> 4;

    for (int i = t; i < 4096; i += 256) ((int4*)w1s)[i] = ((const int4*)w1f)[i];
    for (int i = t; i < 1024; i += 256) ((int4*)w2s)[i] = ((const int4*)w2f)[i];

    int b = row0 + lr;
    if (b >= B) b = B - 1;
    const float* urow = &x[(size_t)uidx[b] * 128];
    const float* vrow = &x[(size_t)(vidx[b] + num_users) * 128];
    bf16x8 ahi[8], alo[8];
#pragma unroll
    for (int kk = 0; kk < 8; ++kk) {
        const float* ap = (kk < 4) ? &urow[kk * 32 + lk * 8] : &vrow[(kk - 4) * 32 + lk * 8];
        float4 v0 = *(const float4*)ap;
        float4 v1 = *(const float4*)(ap + 4);
        float f[8] = {v0.x, v0.y, v0.z, v0.w, v1.x, v1.y, v1.z, v1.w};
#pragma unroll
        for (int j = 0; j < 8; ++j) {
            unsigned short hi = f2bf(f[j]);
            unsigned short lo = f2bf(f[j] - bf2f(hi));
            ((short*)&ahi[kk])[j] = (short)hi;
            ((short*)&alo[kk])[j] = (short)lo;
        }
    }

    f32x4 acc[8];
#pragma unroll
    for (int ct = 0; ct < 8; ++ct) acc[ct] = (f32x4){0.f, 0.f, 0.f, 0.f};

    __syncthreads();

#pragma unroll
    for (int kk = 0; kk < 8; ++kk) {
#pragma unroll
        for (int ct = 0; ct < 8; ++ct) {
            const int fo = ((ct * 8 + kk) * 64 + lane) * 8;
            bf16x8 bhi = *(const bf16x8*)&w1s[fo];
            acc[ct] = __builtin_amdgcn_mfma_f32_16x16x32_bf16(ahi[kk], bhi, acc[ct], 0, 0, 0);
            acc[ct] = __builtin_amdgcn_mfma_f32_16x16x32_bf16(alo[kk], bhi, acc[ct], 0, 0, 0);
        }
    }

#pragma unroll
    for (int ct = 0; ct < 8; ++ct) {
        const int col = ct * 16 + lr;
        const float b1 = mb1[col];
#pragma unroll
        for (int r = 0; r < 4; ++r) {
            float v = fmaxf(acc[ct][r] + b1, 0.f);
            h1s[wave][(lk * 4 + r) * 136 + col] = f2bf(v);
        }
    }
    __syncthreads();

    bf16x8 a2[4];
#pragma unroll
    for (int kk = 0; kk < 4; ++kk)
        a2[kk] = *(const bf16x8*)&h1s[wave][lr * 136 + kk * 32 + lk * 8];

    f32x4 acc2[4];
#pragma unroll
    for (int ct = 0; ct < 4; ++ct) acc2[ct] = (f32x4){0.f, 0.f, 0.f, 0.f};
#pragma unroll
    for (int kk = 0; kk < 4; ++kk) {
#pragma unroll
        for (int ct = 0; ct < 4; ++ct) {
            const int fo = ((ct * 4 + kk) * 64 + lane) * 8;
            bf16x8 bhi = *(const bf16x8*)&w2s[fo];
            acc2[ct] = __builtin_amdgcn_mfma_f32_16x16x32_bf16(a2[kk], bhi, acc2[ct], 0, 0, 0);
        }
    }

    float s[4] = {0.f, 0.f, 0.f, 0.f};
#pragma unroll
    for (int ct = 0; ct < 4; ++ct) {
        const int col = ct * 16 + lr;
        const float b2 = mb2[col];
        const float w3 = mw3[col];
#pragma unroll
        for (int r = 0; r < 4; ++r) {
            float v = fmaxf(acc2[ct][r] + b2, 0.f);
            s[r] = fmaf(v, w3, s[r]);
        }
    }
#pragma unroll
    for (int m = 1; m < 16; m <<= 1) {
#pragma unroll
        for (int r = 0; r < 4; ++r) s[r] += __shfl_xor(s[r], m);
    }
    if (lr == 0) {
        const float b3 = mb3[0];
#pragma unroll
        for (int r = 0; r < 4; ++r) {
            int row = row0 + lk * 4 + r;
            if (row < B) out[row] = 1.0f / (1.0f + expf(-(s[r] + b3)));
        }
    }
}

// ---------------------------------------------------------------------------
// launcher
// ---------------------------------------------------------------------------
extern "C" void kernel_launch(void* const* d_in, const int* in_sizes, int n_in,
                              void* d_out, int out_size, void* d_ws, size_t ws_size,
                              hipStream_t stream) {
    const int* uidx = (const int*)d_in[0];
    const int* vidx = (const int*)d_in[1];
    const int* eidx = (const int*)d_in[2];
    const float* utab = (const float*)d_in[3];
    const float* itab = (const float*)d_in[4];
    const float* W0 = (const float*)d_in[5];
    const float* as0 = (const float*)d_in[6];
    const float* ad0 = (const float*)d_in[7];
    const float* bb0 = (const float*)d_in[8];
    const float* W1 = (const float*)d_in[9];
    const float* as1 = (const float*)d_in[10];
    const float* ad1 = (const float*)d_in[11];
    const float* bb1 = (const float*)d_in[12];
    const float* W2 = (const float*)d_in[13];
    const float* as2 = (const float*)d_in[14];
    const float* ad2 = (const float*)d_in[15];
    const float* bb2 = (const float*)d_in[16];
    const float* ln_g = (const float*)d_in[17];
    const float* ln_b = (const float*)d_in[18];
    const float* mw1 = (const float*)d_in[19];
    const float* mb1 = (const float*)d_in[20];
    const float* mw2 = (const float*)d_in[21];
    const float* mb2 = (const float*)d_in[22];
    const float* mw3 = (const float*)d_in[23];
    const float* mb3 = (const float*)d_in[24];

    const int B = in_sizes[0];
    const int E = in_sizes[2] / 2;
    const int num_users = in_sizes[3] / D128;
    const int num_items = in_sizes[4] / D128;
    const int N = num_users + num_items;
    const int* esrc = eidx;
    const int* edst = eidx + E;

    size_t wsoff = 0;
    auto alloc = [&](size_t bytes) {
        void* p = (char*)d_ws + wsoff;
        wsoff += (bytes + 255) & ~(size_t)255;
        return p;
    };
    float* bufA = (float*)alloc((size_t)N * 128 * 4);
    float* bufB = (float*)alloc((size_t)N * 128 * 4);
    unsigned short* hb = (unsigned short*)alloc((size_t)N * 128 * 2);
    float* aS = (float*)alloc((size_t)N * 4 * 4);
    float* aD = (float*)alloc((size_t)N * 4 * 4);
    float* pbuf = (float*)alloc((size_t)E * 4 * 4);
    int* cnt = (int*)alloc((size_t)(N + 1) * 4);
    int* off = (int*)alloc((size_t)(N + 1) * 4);
    int* cur = (int*)alloc((size_t)(N + 1) * 4);
    int* csr_src = (int*)alloc((size_t)E * 4);
    int* csr_dst = (int*)alloc((size_t)E * 4);
    int* partials = (int*)alloc(64 * 4);
    int* pp = (int*)alloc(64 * 4);
    unsigned short* wb0 = (unsigned short*)alloc(2 * 16384 * 2);
    unsigned short* wb1 = (unsigned short*)alloc(2 * 16384 * 2);
    unsigned short* wb2 = (unsigned short*)alloc(2 * 16384 * 2);
    unsigned short* w1f = (unsigned short*)alloc(32768 * 2);
    unsigned short* w2f = (unsigned short*)alloc(8192 * 2);
    (void)ws_size;

    wrepack3_kernel<<<dim3(64, 3), 256, 0, stream>>>(W0, W1, W2, wb0, wb1, wb2);
    wrepack_mlp_kernel<<<dim3(128, 2), 256, 0, stream>>>(mw1, w1f, mw2, w2f);

    const int NB = (N + SCAN_CHUNK - 1) / SCAN_CHUNK;
    zero_int_kernel<<<(N + 255) / 256, 256, 0, stream>>>(cnt, N);
    count_kernel<<<(E + 255) / 256, 256, 0, stream>>>(edst, E, cnt);
    scan_local_kernel<<<NB, SB, 0, stream>>>(cnt, off, partials, N);
    scan_partials_kernel<<<1, 64, 0, stream>>>(partials, pp, NB, off, N);
    scan_add_kernel<<<(N + 255) / 256, 256, 0, stream>>>(off, cur, pp, N);
    fill_kernel<<<(E + 255) / 256, 256, 0, stream>>>(esrc, edst, E, cur, csr_src, csr_dst);

    const int gemm_grid = (N + 127) / 128;
    const int egrid = (E + 255) / 256;
    const int agrid = (N + 15) / 16;

    // ---- layer 0 (H=4, no residual; X = virtual concat of tables) ----
    gemm_mfma_kernel<4, true><<<gemm_grid, 512, 0, stream>>>(utab, itab, num_users, wb0, as0,
                                                             ad0, hb, aS, aD, N);
    pk4_kernel<<<egrid, 256, 0, stream>>>(csr_src, csr_dst, aS, aD, pbuf, E);
    agg_kernel<4, false><<<agrid, 256, 0, stream>>>(hb, pbuf, off, csr_src, nullptr, bb0, ln_g,
                                                    ln_b, bufB, N);
    // ---- layer 1 (H=4, residual) ----
    gemm_mfma_kernel<4, false><<<gemm_grid, 512, 0, stream>>>(bufB, nullptr, 0, wb1, as1, ad1,
                                                              hb, aS, aD, N);
    pk4_kernel<<<egrid, 256, 0, stream>>>(csr_src, csr_dst, aS, aD, pbuf, E);
    agg_kernel<4, true><<<agrid, 256, 0, stream>>>(hb, pbuf, off, csr_src, bufB, bb1, ln_g,
                                                   ln_b, bufA, N);
    // ---- layer 2 (H=1, residual) ----
    gemm_mfma_kernel<1, false><<<gemm_grid, 512, 0, stream>>>(bufA, nullptr, 0, wb2, as2, ad2,
                                                              hb, aS, aD, N);
    pk1_kernel<<<egrid, 256, 0, stream>>>(csr_src, csr_dst, aS, aD, pbuf, E);
    agg_kernel<1, true><<<agrid, 256, 0, stream>>>(hb, pbuf, off, csr_src, bufA, bb2, ln_g,
                                                   ln_b, bufB, N);

    // ---- prediction MLP (MFMA) ----
    mlp_mfma_kernel<<<(B + 63) / 64, 256, 0, stream>>>(bufB, uidx, vidx, num_users, w1f, mb1,
                                                       w2f, mb2, mw3, mb3, (float*)d_out, B);
}